// Round 1
// baseline (230.852 us; speedup 1.0000x reference)
//
#include <hip/hip_runtime.h>
#include <hip/hip_bf16.h>

#define B_ 2
#define T_ 2048
#define C_ 1024
#define H_ 16
#define D_ 64

typedef __attribute__((ext_vector_type(8))) short bf16x8;   // MFMA A/B operand (8 bf16)
typedef __attribute__((ext_vector_type(4))) float f32x4;    // MFMA C/D
typedef __attribute__((ext_vector_type(8))) unsigned short u16x8;

__device__ __forceinline__ unsigned short f2bf(float f) {
    union { float f; unsigned int u; } v; v.f = f;
    unsigned int r = v.u + 0x7fffu + ((v.u >> 16) & 1u);   // RTN-even
    return (unsigned short)(r >> 16);
}

// ---------------------------------------------------------------------------
// Kernel 1: fused QKV projection.  Z = X[4096,1024] * W^T, W rows = concat(wq,wk,wv)
// Output scattered into qkv[which][b][h][t][d] bf16; q pre-scaled by 0.125.
// ---------------------------------------------------------------------------
__global__ __launch_bounds__(256) void qkv_proj(
    const float* __restrict__ x, const float* __restrict__ wq,
    const float* __restrict__ wk, const float* __restrict__ wv,
    unsigned short* __restrict__ qkv)
{
    __shared__ __align__(16) unsigned short As[128 * 40];
    __shared__ __align__(16) unsigned short Bs[128 * 40];
    const int tid = threadIdx.x;
    const int lane = tid & 63, wave = tid >> 6;
    const int g = lane >> 4, c16 = lane & 15;
    const int bm = blockIdx.x & 31;        // 32 M tiles
    const int bn = blockIdx.x >> 5;        // 24 N tiles
    const int jbase = bn << 7;
    const int which = jbase >> 10;         // 0=q 1=k 2=v (128 | 1024 boundaries)
    const float* wsel = (which == 0) ? wq : (which == 1) ? wk : wv;
    const float* wrow = wsel + (size_t)(jbase & 1023) * C_;
    const float* xrow = x + (size_t)(bm << 7) * C_;

    f32x4 acc[4][4];
#pragma unroll
    for (int i = 0; i < 4; i++)
#pragma unroll
        for (int j = 0; j < 4; j++) acc[i][j] = (f32x4){0.f, 0.f, 0.f, 0.f};

    const int wm = (wave >> 1) << 6, wn = (wave & 1) << 6;
    const int r_st = tid >> 1, h_st = (tid & 1) << 4;

    for (int k0 = 0; k0 < C_; k0 += 32) {
        __syncthreads();
        {   // stage A (x) 128x32 f32 -> bf16
            const float* src = xrow + (size_t)r_st * C_ + k0 + h_st;
            unsigned short tmp[16];
#pragma unroll
            for (int i = 0; i < 16; i += 4) {
                float4 v = *reinterpret_cast<const float4*>(src + i);
                tmp[i] = f2bf(v.x); tmp[i + 1] = f2bf(v.y);
                tmp[i + 2] = f2bf(v.z); tmp[i + 3] = f2bf(v.w);
            }
            *reinterpret_cast<u16x8*>(&As[r_st * 40 + h_st]) = *reinterpret_cast<u16x8*>(tmp);
            *reinterpret_cast<u16x8*>(&As[r_st * 40 + h_st + 8]) = *reinterpret_cast<u16x8*>(tmp + 8);
        }
        {   // stage B (weights) 128x32
            const float* src = wrow + (size_t)r_st * C_ + k0 + h_st;
            unsigned short tmp[16];
#pragma unroll
            for (int i = 0; i < 16; i += 4) {
                float4 v = *reinterpret_cast<const float4*>(src + i);
                tmp[i] = f2bf(v.x); tmp[i + 1] = f2bf(v.y);
                tmp[i + 2] = f2bf(v.z); tmp[i + 3] = f2bf(v.w);
            }
            *reinterpret_cast<u16x8*>(&Bs[r_st * 40 + h_st]) = *reinterpret_cast<u16x8*>(tmp);
            *reinterpret_cast<u16x8*>(&Bs[r_st * 40 + h_st + 8]) = *reinterpret_cast<u16x8*>(tmp + 8);
        }
        __syncthreads();

        bf16x8 af[4], bfr[4];
#pragma unroll
        for (int m = 0; m < 4; m++)
            af[m] = *reinterpret_cast<const bf16x8*>(&As[(wm + m * 16 + c16) * 40 + g * 8]);
#pragma unroll
        for (int n = 0; n < 4; n++)
            bfr[n] = *reinterpret_cast<const bf16x8*>(&Bs[(wn + n * 16 + c16) * 40 + g * 8]);
#pragma unroll
        for (int m = 0; m < 4; m++)
#pragma unroll
            for (int n = 0; n < 4; n++)
                acc[m][n] = __builtin_amdgcn_mfma_f32_16x16x32_bf16(af[m], bfr[n], acc[m][n], 0, 0, 0);
    }

    const float scale = (which == 0) ? 0.125f : 1.0f;
#pragma unroll
    for (int m = 0; m < 4; m++) {
        const int grow = (bm << 7) + wm + m * 16 + (g << 2);
#pragma unroll
        for (int n = 0; n < 4; n++) {
            const int j = jbase + wn + n * 16 + c16;
            const int jj = j & 1023;
            const int h = jj >> 6, d = jj & 63;
#pragma unroll
            for (int r = 0; r < 4; r++) {
                const int row = grow + r;
                const int b = row >> 11, t = row & 2047;
                const size_t off = ((size_t)((which * B_ + b) * H_ + h) * T_ + t) * 64 + d;
                qkv[off] = f2bf(acc[m][n][r] * scale);
            }
        }
    }
}

// ---------------------------------------------------------------------------
// Kernel 2: causal flash attention. 4 waves x 16 q-rows per block, 64-kv tiles.
// ---------------------------------------------------------------------------
__global__ __launch_bounds__(256) void attn(
    const unsigned short* __restrict__ qkv, unsigned short* __restrict__ y)
{
    __shared__ __align__(16) unsigned short Ks[64 * 72];
    __shared__ __align__(16) unsigned short Vt[64 * 72];   // V^T, chunk-XOR swizzled
    __shared__ __align__(16) unsigned short Ps[4][16 * 72];
    const int tid = threadIdx.x, lane = tid & 63, wave = tid >> 6;
    const int g = lane >> 4, c16 = lane & 15;
    const int qt = blockIdx.x & 31;       // T/64
    const int bh = blockIdx.x >> 5;
    const int b = bh >> 4, h = bh & 15;
    const size_t headoff = (size_t)(b * H_ + h) * T_ * 64;
    const size_t QSZ = (size_t)B_ * H_ * T_ * 64;
    const unsigned short* qp = qkv + headoff;
    const unsigned short* kp = qkv + QSZ + headoff;
    const unsigned short* vp = qkv + 2 * QSZ + headoff;
    const int q0 = qt << 6;

    // Q fragments (pre-scaled by 0.125 at projection time)
    bf16x8 qf[2];
    {
        const int qr = q0 + wave * 16 + c16;
        qf[0] = *reinterpret_cast<const bf16x8*>(qp + (size_t)qr * 64 + g * 8);
        qf[1] = *reinterpret_cast<const bf16x8*>(qp + (size_t)qr * 64 + 32 + g * 8);
    }

    float m_run[4] = {-1e30f, -1e30f, -1e30f, -1e30f};
    float l_run[4] = {0.f, 0.f, 0.f, 0.f};
    f32x4 acc_o[4];
#pragma unroll
    for (int i = 0; i < 4; i++) acc_o[i] = (f32x4){0.f, 0.f, 0.f, 0.f};

    const int krow = tid >> 2, kseg = (tid & 3) << 4;       // K staging map
    const int vr2 = (tid >> 3) << 1, vds = (tid & 7) << 3;  // V staging map

    const int nt = qt + 1;
    for (int it = 0; it < nt; ++it) {
        const int s0 = it << 6;
        __syncthreads();
        {   // stage K [64 kv][64 d], row stride 72
            const unsigned short* src = kp + (size_t)(s0 + krow) * 64 + kseg;
            u16x8 a = *reinterpret_cast<const u16x8*>(src);
            u16x8 bv = *reinterpret_cast<const u16x8*>(src + 8);
            *reinterpret_cast<u16x8*>(&Ks[krow * 72 + kseg]) = a;
            *reinterpret_cast<u16x8*>(&Ks[krow * 72 + kseg + 8]) = bv;
        }
        {   // stage V^T [64 d][64 kv], kv pairs packed b32, chunk-XOR swizzle
            const unsigned short* sp = vp + (size_t)(s0 + vr2) * 64 + vds;
            u16x8 v0 = *reinterpret_cast<const u16x8*>(sp);
            u16x8 v1 = *reinterpret_cast<const u16x8*>(sp + 64);
#pragma unroll
            for (int i = 0; i < 8; i++) {
                const int d = vds + i;
                const unsigned int w = (unsigned int)v0[i] | ((unsigned int)v1[i] << 16);
                const int idx = d * 72 + ((((vr2 >> 3) ^ ((d >> 3) & 7)) << 3) | (vr2 & 7));
                *reinterpret_cast<unsigned int*>(&Vt[idx]) = w;
            }
        }
        __syncthreads();

        // S = Q * K^T   (D layout: row q = g*4+r, col kv = f*16+c16)
        f32x4 sf[4];
#pragma unroll
        for (int f = 0; f < 4; f++) sf[f] = (f32x4){0.f, 0.f, 0.f, 0.f};
#pragma unroll
        for (int f = 0; f < 4; f++) {
            bf16x8 k0f = *reinterpret_cast<const bf16x8*>(&Ks[(f * 16 + c16) * 72 + g * 8]);
            bf16x8 k1f = *reinterpret_cast<const bf16x8*>(&Ks[(f * 16 + c16) * 72 + 32 + g * 8]);
            sf[f] = __builtin_amdgcn_mfma_f32_16x16x32_bf16(qf[0], k0f, sf[f], 0, 0, 0);
            sf[f] = __builtin_amdgcn_mfma_f32_16x16x32_bf16(qf[1], k1f, sf[f], 0, 0, 0);
        }

        if (s0 == q0) {   // diagonal tile: causal mask
#pragma unroll
            for (int f = 0; f < 4; f++)
#pragma unroll
                for (int r = 0; r < 4; r++) {
                    const int qg = q0 + wave * 16 + g * 4 + r;
                    const int kg = s0 + f * 16 + c16;
                    if (kg > qg) sf[f][r] = -1e30f;
                }
        }

        // online softmax
#pragma unroll
        for (int r = 0; r < 4; r++) {
            float mx = fmaxf(fmaxf(sf[0][r], sf[1][r]), fmaxf(sf[2][r], sf[3][r]));
#pragma unroll
            for (int sh = 1; sh < 16; sh <<= 1) mx = fmaxf(mx, __shfl_xor(mx, sh, 64));
            const float mn = fmaxf(m_run[r], mx);
            const float corr = __expf(m_run[r] - mn);
            m_run[r] = mn;
            float ssum = 0.f;
#pragma unroll
            for (int f = 0; f < 4; f++) {
                const float p = __expf(sf[f][r] - mn);
                sf[f][r] = p;
                ssum += p;
            }
#pragma unroll
            for (int sh = 1; sh < 16; sh <<= 1) ssum += __shfl_xor(ssum, sh, 64);
            l_run[r] = l_run[r] * corr + ssum;
#pragma unroll
            for (int fd = 0; fd < 4; fd++) acc_o[fd][r] *= corr;
        }

        // P -> LDS (per-wave region) in A-operand layout source
#pragma unroll
        for (int f = 0; f < 4; f++)
#pragma unroll
            for (int r = 0; r < 4; r++)
                Ps[wave][(g * 4 + r) * 72 + f * 16 + c16] = f2bf(sf[f][r]);

        // O += P * V
#pragma unroll
        for (int ks = 0; ks < 2; ks++) {
            bf16x8 pa = *reinterpret_cast<const bf16x8*>(&Ps[wave][c16 * 72 + ks * 32 + g * 8]);
#pragma unroll
            for (int fd = 0; fd < 4; fd++) {
                const int d = fd * 16 + c16;
                const int cc = ks * 4 + g;
                bf16x8 vf = *reinterpret_cast<const bf16x8*>(
                    &Vt[d * 72 + ((cc ^ ((d >> 3) & 7)) << 3)]);
                acc_o[fd] = __builtin_amdgcn_mfma_f32_16x16x32_bf16(pa, vf, acc_o[fd], 0, 0, 0);
            }
        }
    }

    // epilogue: y[b][t][h*64+d] bf16
    const int trow = q0 + wave * 16 + g * 4;
#pragma unroll
    for (int fd = 0; fd < 4; fd++)
#pragma unroll
        for (int r = 0; r < 4; r++) {
            const float v = acc_o[fd][r] / l_run[r];
            y[((size_t)b * T_ + trow + r) * 1024 + h * 64 + fd * 16 + c16] = f2bf(v);
        }
}

// ---------------------------------------------------------------------------
// Kernel 3: out = y[4096,1024](bf16) @ w_o[1024,1024](f32) -> f32
// ---------------------------------------------------------------------------
__global__ __launch_bounds__(256) void out_proj(
    const unsigned short* __restrict__ y, const float* __restrict__ wo,
    float* __restrict__ out)
{
    __shared__ __align__(16) unsigned short As[128 * 40];
    __shared__ __align__(16) unsigned short Bt[128 * 40];   // B^T: [n][k]
    const int tid = threadIdx.x;
    const int lane = tid & 63, wave = tid >> 6;
    const int g = lane >> 4, c16 = lane & 15;
    const int bm = blockIdx.x & 31;   // 32 M tiles
    const int bn = blockIdx.x >> 5;   // 8 N tiles
    const int wm = (wave >> 1) << 6, wn = (wave & 1) << 6;

    f32x4 acc[4][4];
#pragma unroll
    for (int i = 0; i < 4; i++)
#pragma unroll
        for (int j = 0; j < 4; j++) acc[i][j] = (f32x4){0.f, 0.f, 0.f, 0.f};

    const int r_st = tid >> 1, h_st = (tid & 1) << 4;
    const int kk2 = (tid & 15) << 1, nseg = (tid >> 4) << 3;

    for (int k0 = 0; k0 < 1024; k0 += 32) {
        __syncthreads();
        {   // stage A (y, already bf16)
            const unsigned short* src = y + (size_t)((bm << 7) + r_st) * 1024 + k0 + h_st;
            *reinterpret_cast<u16x8*>(&As[r_st * 40 + h_st]) = *reinterpret_cast<const u16x8*>(src);
            *reinterpret_cast<u16x8*>(&As[r_st * 40 + h_st + 8]) = *reinterpret_cast<const u16x8*>(src + 8);
        }
        {   // stage B transposed: w_o rows k0..k0+31, cols bn*128..+128
            const float* sp = wo + (size_t)(k0 + kk2) * 1024 + (bn << 7) + nseg;
            float4 a0 = *reinterpret_cast<const float4*>(sp);
            float4 a1 = *reinterpret_cast<const float4*>(sp + 4);
            float4 b0 = *reinterpret_cast<const float4*>(sp + 1024);
            float4 b1 = *reinterpret_cast<const float4*>(sp + 1028);
            float va[8] = {a0.x, a0.y, a0.z, a0.w, a1.x, a1.y, a1.z, a1.w};
            float vb[8] = {b0.x, b0.y, b0.z, b0.w, b1.x, b1.y, b1.z, b1.w};
#pragma unroll
            for (int i = 0; i < 8; i++) {
                const unsigned int w =
                    (unsigned int)f2bf(va[i]) | ((unsigned int)f2bf(vb[i]) << 16);
                *reinterpret_cast<unsigned int*>(&Bt[(nseg + i) * 40 + kk2]) = w;
            }
        }
        __syncthreads();

        bf16x8 af[4], bfr[4];
#pragma unroll
        for (int m = 0; m < 4; m++)
            af[m] = *reinterpret_cast<const bf16x8*>(&As[(wm + m * 16 + c16) * 40 + g * 8]);
#pragma unroll
        for (int n = 0; n < 4; n++)
            bfr[n] = *reinterpret_cast<const bf16x8*>(&Bt[(wn + n * 16 + c16) * 40 + g * 8]);
#pragma unroll
        for (int m = 0; m < 4; m++)
#pragma unroll
            for (int n = 0; n < 4; n++)
                acc[m][n] = __builtin_amdgcn_mfma_f32_16x16x32_bf16(af[m], bfr[n], acc[m][n], 0, 0, 0);
    }

#pragma unroll
    for (int m = 0; m < 4; m++) {
        const int grow = (bm << 7) + wm + m * 16 + (g << 2);
#pragma unroll
        for (int n = 0; n < 4; n++) {
            const int gcol = (bn << 7) + wn + n * 16 + c16;
#pragma unroll
            for (int r = 0; r < 4; r++)
                out[(size_t)(grow + r) * 1024 + gcol] = acc[m][n][r];
        }
    }
}

extern "C" void kernel_launch(void* const* d_in, const int* in_sizes, int n_in,
                              void* d_out, int out_size, void* d_ws, size_t ws_size,
                              hipStream_t stream) {
    const float* x  = (const float*)d_in[0];
    const float* wq = (const float*)d_in[1];
    const float* wk = (const float*)d_in[2];
    const float* wv = (const float*)d_in[3];
    const float* wo = (const float*)d_in[4];
    float* out = (float*)d_out;

    unsigned short* qkv = (unsigned short*)d_ws;                 // 3*B*H*T*64 bf16
    unsigned short* y   = qkv + (size_t)3 * B_ * H_ * T_ * 64;   // B*T*1024 bf16

    qkv_proj<<<dim3(32 * 24), 256, 0, stream>>>(x, wq, wk, wv, qkv);
    attn<<<dim3(32 * B_ * H_), 256, 0, stream>>>(qkv, y);
    out_proj<<<dim3(32 * 8), 256, 0, stream>>>(y, wo, out);
}

// Round 2
// 158.319 us; speedup vs baseline: 1.4581x; 1.4581x over previous
//
#include <hip/hip_runtime.h>
#include <hip/hip_bf16.h>

#define B_ 2
#define T_ 2048
#define C_ 1024
#define H_ 16
#define D_ 64

typedef __attribute__((ext_vector_type(8))) short bf16x8;   // MFMA A/B operand (8 bf16)
typedef __attribute__((ext_vector_type(4))) float f32x4;    // MFMA C/D
typedef __attribute__((ext_vector_type(8))) unsigned short u16x8;
typedef __attribute__((ext_vector_type(2))) unsigned int u32x2;

__device__ __forceinline__ unsigned short f2bf(float f) {
    union { float f; unsigned int u; } v; v.f = f;
    unsigned int r = v.u + 0x7fffu + ((v.u >> 16) & 1u);   // RTN-even
    return (unsigned short)(r >> 16);
}

// ---------------------------------------------------------------------------
// Kernel 1: fused QKV projection.  Z = X[4096,1024] * W^T
// q pre-scaled by 0.125*log2(e) (exp2-based softmax downstream).
// ---------------------------------------------------------------------------
__global__ __launch_bounds__(256) void qkv_proj(
    const float* __restrict__ x, const float* __restrict__ wq,
    const float* __restrict__ wk, const float* __restrict__ wv,
    unsigned short* __restrict__ qkv)
{
    __shared__ __align__(16) unsigned short As[128 * 40];
    __shared__ __align__(16) unsigned short Bs[128 * 40];
    const int tid = threadIdx.x;
    const int lane = tid & 63, wave = tid >> 6;
    const int g = lane >> 4, c16 = lane & 15;
    const int bm = blockIdx.x & 31;        // 32 M tiles
    const int bn = blockIdx.x >> 5;        // 24 N tiles
    const int jbase = bn << 7;
    const int which = jbase >> 10;         // 0=q 1=k 2=v
    const float* wsel = (which == 0) ? wq : (which == 1) ? wk : wv;
    const float* wrow = wsel + (size_t)(jbase & 1023) * C_;
    const float* xrow = x + (size_t)(bm << 7) * C_;

    f32x4 acc[4][4];
#pragma unroll
    for (int i = 0; i < 4; i++)
#pragma unroll
        for (int j = 0; j < 4; j++) acc[i][j] = (f32x4){0.f, 0.f, 0.f, 0.f};

    const int wm = (wave >> 1) << 6, wn = (wave & 1) << 6;
    const int r_st = tid >> 1, h_st = (tid & 1) << 4;

    for (int k0 = 0; k0 < C_; k0 += 32) {
        __syncthreads();
        {
            const float* src = xrow + (size_t)r_st * C_ + k0 + h_st;
            unsigned short tmp[16];
#pragma unroll
            for (int i = 0; i < 16; i += 4) {
                float4 v = *reinterpret_cast<const float4*>(src + i);
                tmp[i] = f2bf(v.x); tmp[i + 1] = f2bf(v.y);
                tmp[i + 2] = f2bf(v.z); tmp[i + 3] = f2bf(v.w);
            }
            *reinterpret_cast<u16x8*>(&As[r_st * 40 + h_st]) = *reinterpret_cast<u16x8*>(tmp);
            *reinterpret_cast<u16x8*>(&As[r_st * 40 + h_st + 8]) = *reinterpret_cast<u16x8*>(tmp + 8);
        }
        {
            const float* src = wrow + (size_t)r_st * C_ + k0 + h_st;
            unsigned short tmp[16];
#pragma unroll
            for (int i = 0; i < 16; i += 4) {
                float4 v = *reinterpret_cast<const float4*>(src + i);
                tmp[i] = f2bf(v.x); tmp[i + 1] = f2bf(v.y);
                tmp[i + 2] = f2bf(v.z); tmp[i + 3] = f2bf(v.w);
            }
            *reinterpret_cast<u16x8*>(&Bs[r_st * 40 + h_st]) = *reinterpret_cast<u16x8*>(tmp);
            *reinterpret_cast<u16x8*>(&Bs[r_st * 40 + h_st + 8]) = *reinterpret_cast<u16x8*>(tmp + 8);
        }
        __syncthreads();

        bf16x8 af[4], bfr[4];
#pragma unroll
        for (int m = 0; m < 4; m++)
            af[m] = *reinterpret_cast<const bf16x8*>(&As[(wm + m * 16 + c16) * 40 + g * 8]);
#pragma unroll
        for (int n = 0; n < 4; n++)
            bfr[n] = *reinterpret_cast<const bf16x8*>(&Bs[(wn + n * 16 + c16) * 40 + g * 8]);
#pragma unroll
        for (int m = 0; m < 4; m++)
#pragma unroll
            for (int n = 0; n < 4; n++)
                acc[m][n] = __builtin_amdgcn_mfma_f32_16x16x32_bf16(af[m], bfr[n], acc[m][n], 0, 0, 0);
    }

    const float scale = (which == 0) ? 0.125f * 1.4426950408889634f : 1.0f;
#pragma unroll
    for (int m = 0; m < 4; m++) {
        const int grow = (bm << 7) + wm + m * 16 + (g << 2);
#pragma unroll
        for (int n = 0; n < 4; n++) {
            const int j = jbase + wn + n * 16 + c16;
            const int jj = j & 1023;
            const int h = jj >> 6, d = jj & 63;
#pragma unroll
            for (int r = 0; r < 4; r++) {
                const int row = grow + r;
                const int b = row >> 11, t = row & 2047;
                const size_t off = ((size_t)((which * B_ + b) * H_ + h) * T_ + t) * 64 + d;
                qkv[off] = f2bf(acc[m][n][r] * scale);
            }
        }
    }
}

// ---------------------------------------------------------------------------
// Kernel 2: causal flash attention, transposed (S^T / O^T) form.
// Block = pair of q-tiles {p, 31-p} (uniform work), 4 waves x 16 q-rows each.
// Softmax lane-local per q (q = lane&15), kv spread over 16 regs x 4 g-lanes.
// ---------------------------------------------------------------------------
__device__ __forceinline__ void attn_tile(
    const unsigned short* __restrict__ Ks, const unsigned short* __restrict__ Vt,
    unsigned short* __restrict__ Psw,
    const bf16x8& qf0, const bf16x8& qf1,
    float& m_run, float& l_run, f32x4* acc,
    int qglob, int s0, bool diag, int g, int c16)
{
    f32x4 sfT[4];
#pragma unroll
    for (int f = 0; f < 4; f++) sfT[f] = (f32x4){0.f, 0.f, 0.f, 0.f};

    // S^T[kv][q] = K · Q^T  (A = K frag, B = Q frag)
#pragma unroll
    for (int f = 0; f < 4; f++) {
        const int row = f * 16 + c16;
        const int sw = row & 7;
        bf16x8 k0 = *reinterpret_cast<const bf16x8*>(&Ks[(row << 6) + ((g ^ sw) << 3)]);
        bf16x8 k1 = *reinterpret_cast<const bf16x8*>(&Ks[(row << 6) + (((g + 4) ^ sw) << 3)]);
        sfT[f] = __builtin_amdgcn_mfma_f32_16x16x32_bf16(k0, qf0, sfT[f], 0, 0, 0);
        sfT[f] = __builtin_amdgcn_mfma_f32_16x16x32_bf16(k1, qf1, sfT[f], 0, 0, 0);
    }

    if (diag) {
#pragma unroll
        for (int f = 0; f < 4; f++)
#pragma unroll
            for (int r = 0; r < 4; r++) {
                const int kv = s0 + f * 16 + g * 4 + r;
                if (kv > qglob) sfT[f][r] = -1e30f;
            }
    }

    // online softmax, lane-local per q=c16 (cross-g reduce only)
    float mloc = -1e30f;
#pragma unroll
    for (int f = 0; f < 4; f++)
#pragma unroll
        for (int r = 0; r < 4; r++) mloc = fmaxf(mloc, sfT[f][r]);
    mloc = fmaxf(mloc, __shfl_xor(mloc, 16, 64));
    mloc = fmaxf(mloc, __shfl_xor(mloc, 32, 64));
    const float mn = fmaxf(m_run, mloc);
    const float corr = __builtin_amdgcn_exp2f(m_run - mn);
    m_run = mn;
    float ssum = 0.f;
#pragma unroll
    for (int f = 0; f < 4; f++)
#pragma unroll
        for (int r = 0; r < 4; r++) {
            const float pv = __builtin_amdgcn_exp2f(sfT[f][r] - mn);
            sfT[f][r] = pv;
            ssum += pv;
        }
    ssum += __shfl_xor(ssum, 16, 64);
    ssum += __shfl_xor(ssum, 32, 64);
    l_run = l_run * corr + ssum;
#pragma unroll
    for (int fd = 0; fd < 4; fd++)
#pragma unroll
        for (int r = 0; r < 4; r++) acc[fd][r] *= corr;

    // P[q=c16][kv] -> per-wave LDS (b64 packed, kv = f*16+g*4+r)
#pragma unroll
    for (int f = 0; f < 4; f++) {
        u32x2 w;
        w[0] = (unsigned int)f2bf(sfT[f][0]) | ((unsigned int)f2bf(sfT[f][1]) << 16);
        w[1] = (unsigned int)f2bf(sfT[f][2]) | ((unsigned int)f2bf(sfT[f][3]) << 16);
        *reinterpret_cast<u32x2*>(&Psw[c16 * 72 + f * 16 + g * 4]) = w;
    }

    // O^T[d][q] += V^T · P   (A = V^T frag, B = P frag)
#pragma unroll
    for (int ks = 0; ks < 2; ks++) {
        bf16x8 pa = *reinterpret_cast<const bf16x8*>(&Psw[c16 * 72 + ks * 32 + (g << 3)]);
#pragma unroll
        for (int fd = 0; fd < 4; fd++) {
            const int d = fd * 16 + c16;
            bf16x8 vf = *reinterpret_cast<const bf16x8*>(
                &Vt[d * 72 + ((((ks << 2) + g) ^ ((d >> 3) & 7)) << 3)]);
            acc[fd] = __builtin_amdgcn_mfma_f32_16x16x32_bf16(vf, pa, acc[fd], 0, 0, 0);
        }
    }
}

__global__ __launch_bounds__(256) void attn(
    const unsigned short* __restrict__ qkv, unsigned short* __restrict__ y)
{
    __shared__ __align__(16) unsigned short Ks[64 * 64];   // XOR-swizzled chunks
    __shared__ __align__(16) unsigned short Vt[64 * 72];   // V^T, chunk-XOR swizzled
    __shared__ __align__(16) unsigned short Ps[4][16 * 72];
    const int tid = threadIdx.x, lane = tid & 63, wave = tid >> 6;
    const int g = lane >> 4, c16 = lane & 15;
    const int p = blockIdx.x & 15;        // pair index
    const int bh = blockIdx.x >> 4;
    const int b = bh >> 4, h = bh & 15;
    const size_t headoff = (size_t)(b * H_ + h) * T_ * 64;
    const size_t QSZ = (size_t)B_ * H_ * T_ * 64;
    const unsigned short* qp = qkv + headoff;
    const unsigned short* kp = qkv + QSZ + headoff;
    const unsigned short* vp = qkv + 2 * QSZ + headoff;

    const int tA = p, tB = 31 - p;
    const int qbaseA = (tA << 6) + wave * 16, qbaseB = (tB << 6) + wave * 16;

    bf16x8 qfA[2], qfB[2];
    {
        const size_t ra = (size_t)(qbaseA + c16) * 64, rb = (size_t)(qbaseB + c16) * 64;
        qfA[0] = *reinterpret_cast<const bf16x8*>(qp + ra + g * 8);
        qfA[1] = *reinterpret_cast<const bf16x8*>(qp + ra + 32 + g * 8);
        qfB[0] = *reinterpret_cast<const bf16x8*>(qp + rb + g * 8);
        qfB[1] = *reinterpret_cast<const bf16x8*>(qp + rb + 32 + g * 8);
    }

    float mA = -1e30f, lA = 0.f, mB = -1e30f, lB = 0.f;
    f32x4 accA[4], accB[4];
#pragma unroll
    for (int i = 0; i < 4; i++) {
        accA[i] = (f32x4){0.f, 0.f, 0.f, 0.f};
        accB[i] = (f32x4){0.f, 0.f, 0.f, 0.f};
    }

    const int krow = tid >> 2, kc2 = (tid & 3) << 1;        // K staging map
    const int vr2 = (tid >> 3) << 1, vds = (tid & 7) << 3;  // V staging map

    const int nt = 32 - p;   // kv tiles 0..tB
    for (int it = 0; it < nt; ++it) {
        const int s0 = it << 6;
        __syncthreads();
        {   // stage K [64 kv][64 d], chunk-XOR swizzle (both sides)
            const unsigned short* src = kp + (size_t)(s0 + krow) * 64 + (kc2 << 3);
            u16x8 a0 = *reinterpret_cast<const u16x8*>(src);
            u16x8 a1 = *reinterpret_cast<const u16x8*>(src + 8);
            const int sw = krow & 7;
            *reinterpret_cast<u16x8*>(&Ks[(krow << 6) + ((kc2 ^ sw) << 3)]) = a0;
            *reinterpret_cast<u16x8*>(&Ks[(krow << 6) + (((kc2 + 1) ^ sw) << 3)]) = a1;
        }
        {   // stage V^T [64 d][64 kv], kv pairs packed b32, chunk-XOR swizzle
            const unsigned short* sp = vp + (size_t)(s0 + vr2) * 64 + vds;
            u16x8 v0 = *reinterpret_cast<const u16x8*>(sp);
            u16x8 v1 = *reinterpret_cast<const u16x8*>(sp + 64);
#pragma unroll
            for (int i = 0; i < 8; i++) {
                const int d = vds + i;
                const unsigned int w = (unsigned int)v0[i] | ((unsigned int)v1[i] << 16);
                const int idx = d * 72 + ((((vr2 >> 3) ^ ((d >> 3) & 7)) << 3) | (vr2 & 7));
                *reinterpret_cast<unsigned int*>(&Vt[idx]) = w;
            }
        }
        __syncthreads();

        attn_tile(Ks, Vt, Ps[wave], qfB[0], qfB[1], mB, lB, accB,
                  qbaseB + c16, s0, it == tB, g, c16);
        if (it <= tA)
            attn_tile(Ks, Vt, Ps[wave], qfA[0], qfA[1], mA, lA, accA,
                      qbaseA + c16, s0, it == tA, g, c16);
    }

    // epilogue: y[b][t][h*64+d], lane-local l, d = fd*16 + g*4 + r
    const float liA = 1.0f / lA, liB = 1.0f / lB;
#pragma unroll
    for (int fd = 0; fd < 4; fd++) {
        u32x2 wa, wb;
        wa[0] = (unsigned int)f2bf(accA[fd][0] * liA) | ((unsigned int)f2bf(accA[fd][1] * liA) << 16);
        wa[1] = (unsigned int)f2bf(accA[fd][2] * liA) | ((unsigned int)f2bf(accA[fd][3] * liA) << 16);
        wb[0] = (unsigned int)f2bf(accB[fd][0] * liB) | ((unsigned int)f2bf(accB[fd][1] * liB) << 16);
        wb[1] = (unsigned int)f2bf(accB[fd][2] * liB) | ((unsigned int)f2bf(accB[fd][3] * liB) << 16);
        const size_t ca = ((size_t)b * T_ + qbaseA + c16) * 1024 + h * 64 + fd * 16 + g * 4;
        const size_t cb = ((size_t)b * T_ + qbaseB + c16) * 1024 + h * 64 + fd * 16 + g * 4;
        *reinterpret_cast<u32x2*>(&y[ca]) = wa;
        *reinterpret_cast<u32x2*>(&y[cb]) = wb;
    }
}

// ---------------------------------------------------------------------------
// Kernel 3: out = y[4096,1024](bf16) @ w_o[1024,1024](f32) -> f32
// ---------------------------------------------------------------------------
__global__ __launch_bounds__(256) void out_proj(
    const unsigned short* __restrict__ y, const float* __restrict__ wo,
    float* __restrict__ out)
{
    __shared__ __align__(16) unsigned short As[128 * 40];
    __shared__ __align__(16) unsigned short Bt[128 * 40];   // B^T: [n][k]
    const int tid = threadIdx.x;
    const int lane = tid & 63, wave = tid >> 6;
    const int g = lane >> 4, c16 = lane & 15;
    const int bm = blockIdx.x & 31;   // 32 M tiles
    const int bn = blockIdx.x >> 5;   // 8 N tiles
    const int wm = (wave >> 1) << 6, wn = (wave & 1) << 6;

    f32x4 acc[4][4];
#pragma unroll
    for (int i = 0; i < 4; i++)
#pragma unroll
        for (int j = 0; j < 4; j++) acc[i][j] = (f32x4){0.f, 0.f, 0.f, 0.f};

    const int r_st = tid >> 1, h_st = (tid & 1) << 4;
    const int kk2 = (tid & 15) << 1, nseg = (tid >> 4) << 3;

    for (int k0 = 0; k0 < 1024; k0 += 32) {
        __syncthreads();
        {
            const unsigned short* src = y + (size_t)((bm << 7) + r_st) * 1024 + k0 + h_st;
            *reinterpret_cast<u16x8*>(&As[r_st * 40 + h_st]) = *reinterpret_cast<const u16x8*>(src);
            *reinterpret_cast<u16x8*>(&As[r_st * 40 + h_st + 8]) = *reinterpret_cast<const u16x8*>(src + 8);
        }
        {
            const float* sp = wo + (size_t)(k0 + kk2) * 1024 + (bn << 7) + nseg;
            float4 a0 = *reinterpret_cast<const float4*>(sp);
            float4 a1 = *reinterpret_cast<const float4*>(sp + 4);
            float4 b0 = *reinterpret_cast<const float4*>(sp + 1024);
            float4 b1 = *reinterpret_cast<const float4*>(sp + 1028);
            float va[8] = {a0.x, a0.y, a0.z, a0.w, a1.x, a1.y, a1.z, a1.w};
            float vb[8] = {b0.x, b0.y, b0.z, b0.w, b1.x, b1.y, b1.z, b1.w};
#pragma unroll
            for (int i = 0; i < 8; i++) {
                const unsigned int w =
                    (unsigned int)f2bf(va[i]) | ((unsigned int)f2bf(vb[i]) << 16);
                *reinterpret_cast<unsigned int*>(&Bt[(nseg + i) * 40 + kk2]) = w;
            }
        }
        __syncthreads();

        bf16x8 af[4], bfr[4];
#pragma unroll
        for (int m = 0; m < 4; m++)
            af[m] = *reinterpret_cast<const bf16x8*>(&As[(wm + m * 16 + c16) * 40 + g * 8]);
#pragma unroll
        for (int n = 0; n < 4; n++)
            bfr[n] = *reinterpret_cast<const bf16x8*>(&Bt[(wn + n * 16 + c16) * 40 + g * 8]);
#pragma unroll
        for (int m = 0; m < 4; m++)
#pragma unroll
            for (int n = 0; n < 4; n++)
                acc[m][n] = __builtin_amdgcn_mfma_f32_16x16x32_bf16(af[m], bfr[n], acc[m][n], 0, 0, 0);
    }

#pragma unroll
    for (int m = 0; m < 4; m++) {
        const int grow = (bm << 7) + wm + m * 16 + (g << 2);
#pragma unroll
        for (int n = 0; n < 4; n++) {
            const int gcol = (bn << 7) + wn + n * 16 + c16;
#pragma unroll
            for (int r = 0; r < 4; r++)
                out[(size_t)(grow + r) * 1024 + gcol] = acc[m][n][r];
        }
    }
}

extern "C" void kernel_launch(void* const* d_in, const int* in_sizes, int n_in,
                              void* d_out, int out_size, void* d_ws, size_t ws_size,
                              hipStream_t stream) {
    const float* x  = (const float*)d_in[0];
    const float* wq = (const float*)d_in[1];
    const float* wk = (const float*)d_in[2];
    const float* wv = (const float*)d_in[3];
    const float* wo = (const float*)d_in[4];
    float* out = (float*)d_out;

    unsigned short* qkv = (unsigned short*)d_ws;                 // 3*B*H*T*64 bf16
    unsigned short* y   = qkv + (size_t)3 * B_ * H_ * T_ * 64;   // B*T*1024 bf16

    qkv_proj<<<dim3(32 * 24), 256, 0, stream>>>(x, wq, wk, wv, qkv);
    attn<<<dim3(16 * B_ * H_), 256, 0, stream>>>(qkv, y);
    out_proj<<<dim3(32 * 8), 256, 0, stream>>>(y, wo, out);
}